// Round 1
// baseline (74.156 us; speedup 1.0000x reference)
//
#include <hip/hip_runtime.h>

// ShiftDisLoss: per-box BEV corner distance loss, weighted global sum / B.
// Inputs (setup_inputs order): pred_bbox3d [B,N,7] f32, gt_bbox3d [B,N,7] f32,
// weights [B,N] f32. Output: 1 f32 scalar. B=4, N=1e6 fixed by setup_inputs.

struct C4 { float x0, y0, x1, y1, x2, y2, x3, y3; };

// stable adjacent compare-exchange (swap only on strictly-greater key)
__device__ __forceinline__ void ce3(float& ka, float& xa, float& ya,
                                    float& kb, float& xb, float& yb) {
    if (ka > kb) {
        float t;
        t = ka; ka = kb; kb = t;
        t = xa; xa = xb; xb = t;
        t = ya; ya = yb; yb = t;
    }
}

__device__ __forceinline__ C4 sorted_corners(float cx, float cy,
                                             float dx, float dy, float h) {
    float s = sinf(h), c = cosf(h);
    float hx = 0.5f * dx, hy = 0.5f * dy;
    float xc = hx * c, xs = hx * s, yc = hy * c, ys = hy * s;
    // tmpl order: (+,+), (+,-), (-,-), (-,+)  (scaled by 0.5*dims)
    float x0 =  xc - ys + cx, y0 =  xs + yc + cy;
    float x1 =  xc + ys + cx, y1 =  xs - yc + cy;
    float x2 = -xc + ys + cx, y2 = -xs - yc + cy;
    float x3 = -xc - ys + cx, y3 = -xs + yc + cy;

    float k0 = x0 * x0 + y0 * y0;
    float k1 = x1 * x1 + y1 * y1;
    float k2 = x2 * x2 + y2 * y2;
    float k3 = x3 * x3 + y3 * y3;

    // stable ascending sort of 4 by key (bubble network, adjacent swaps only)
    ce3(k0, x0, y0, k1, x1, y1);
    ce3(k1, x1, y1, k2, x2, y2);
    ce3(k2, x2, y2, k3, x3, y3);
    ce3(k0, x0, y0, k1, x1, y1);
    ce3(k1, x1, y1, k2, x2, y2);
    ce3(k0, x0, y0, k1, x1, y1);

    // middle two re-sorted (stable) by x^2
    float m1 = x1 * x1, m2 = x2 * x2;
    if (m1 > m2) {
        float t;
        t = x1; x1 = x2; x2 = t;
        t = y1; y1 = y2; y2 = t;
    }
    C4 r = { x0, y0, x1, y1, x2, y2, x3, y3 };
    return r;
}

__device__ __forceinline__ float ptl_sq(float px, float py,
                                        float lx1, float ly1,
                                        float lx2, float ly2) {
    float dy = ly2 - ly1, dx = lx2 - lx1;
    float num = dy * px - dx * py + lx2 * ly1 - ly2 * lx1;
    float den = dy * dy + dx * dx;
    return num * num / den;
}

__device__ __forceinline__ float box_loss(float pcx, float pcy, float pdx,
                                          float pdy, float ph,
                                          float gcx, float gcy, float gdx,
                                          float gdy, float gh) {
    C4 p = sorted_corners(pcx, pcy, pdx, pdy, ph);
    C4 g = sorted_corners(gcx, gcy, gdx, gdy, gh);
    float ddx = g.x1 - g.x2, ddy = g.y1 - g.y2;
    float diag = ddx * ddx + ddy * ddy;
    float d = ptl_sq(p.x1, p.y1, g.x0, g.y0, g.x1, g.y1)
            + ptl_sq(p.x2, p.y2, g.x0, g.y0, g.x2, g.y2)
            + ptl_sq(p.x0, p.y0, g.x0, g.y0, g.x3, g.y3);
    return d / diag;
}

__global__ __launch_bounds__(256)
void shiftdis_loss_kernel(const float* __restrict__ pred,
                          const float* __restrict__ gt,
                          const float* __restrict__ w,
                          float* __restrict__ out,
                          long long n_boxes, float inv_b) {
    long long gidx = (long long)blockIdx.x * blockDim.x + threadIdx.x;
    long long b0 = gidx * 4;
    float acc = 0.0f;

    if (b0 + 4 <= n_boxes) {
        // 4 boxes = 28 floats = 7 aligned float4 per tensor
        const float4* p4 = reinterpret_cast<const float4*>(pred + b0 * 7);
        const float4* g4 = reinterpret_cast<const float4*>(gt + b0 * 7);
        float pf[28], gf[28];
#pragma unroll
        for (int i = 0; i < 7; ++i) {
            float4 v = p4[i];
            pf[4 * i + 0] = v.x; pf[4 * i + 1] = v.y;
            pf[4 * i + 2] = v.z; pf[4 * i + 3] = v.w;
            float4 u = g4[i];
            gf[4 * i + 0] = u.x; gf[4 * i + 1] = u.y;
            gf[4 * i + 2] = u.z; gf[4 * i + 3] = u.w;
        }
        float4 wv = *reinterpret_cast<const float4*>(w + b0);
        float wa0 = wv.x, wa1 = wv.y, wa2 = wv.z, wa3 = wv.w;

#pragma unroll
        for (int j = 0; j < 4; ++j) {
            float wj = (j == 0) ? wa0 : (j == 1) ? wa1 : (j == 2) ? wa2 : wa3;
            acc += box_loss(pf[7 * j + 0], pf[7 * j + 1], pf[7 * j + 3],
                            pf[7 * j + 4], pf[7 * j + 6],
                            gf[7 * j + 0], gf[7 * j + 1], gf[7 * j + 3],
                            gf[7 * j + 4], gf[7 * j + 6]) * wj;
        }
    } else if (b0 < n_boxes) {
        for (long long b = b0; b < n_boxes; ++b) {
            const float* p = pred + b * 7;
            const float* q = gt + b * 7;
            acc += box_loss(p[0], p[1], p[3], p[4], p[6],
                            q[0], q[1], q[3], q[4], q[6]) * w[b];
        }
    }

    // wave-64 reduce
#pragma unroll
    for (int off = 32; off > 0; off >>= 1)
        acc += __shfl_down(acc, off, 64);

    __shared__ float wsum[4];
    int lane = threadIdx.x & 63;
    int wid = threadIdx.x >> 6;
    if (lane == 0) wsum[wid] = acc;
    __syncthreads();
    if (threadIdx.x == 0) {
        float bsum = wsum[0] + wsum[1] + wsum[2] + wsum[3];
        atomicAdd(out, bsum * inv_b);
    }
}

extern "C" void kernel_launch(void* const* d_in, const int* in_sizes, int n_in,
                              void* d_out, int out_size, void* d_ws, size_t ws_size,
                              hipStream_t stream) {
    const float* pred = (const float*)d_in[0];
    const float* gt   = (const float*)d_in[1];
    const float* w    = (const float*)d_in[2];
    float* out = (float*)d_out;

    long long n_boxes = (long long)in_sizes[2];   // B*N
    const float inv_b = 0.25f;                    // B = 4 (fixed by setup_inputs)

    // harness poisons d_out once and never re-poisons between replays
    hipMemsetAsync(d_out, 0, sizeof(float), stream);

    long long groups = (n_boxes + 3) / 4;
    int block = 256;
    long long grid = (groups + block - 1) / block;
    shiftdis_loss_kernel<<<(int)grid, block, 0, stream>>>(pred, gt, w, out,
                                                          n_boxes, inv_b);
}